// Round 8
// baseline (336.125 us; speedup 1.0000x reference)
//
#include <hip/hip_runtime.h>

#define NF 128
#define NC 64
#define NBMAX 512          // max dst-buckets (N/256 = 391 for N=100000)
#define TPART 8192         // edges per k_part block
#define LDA 132            // k-major LDS pad: 132*4 % 16 == 0 -> aligned b128 reads

static inline size_t alignup(size_t x){ return (x + 255) & ~(size_t)255; }

__device__ __forceinline__ unsigned short f2bf(float f){
  unsigned u = __float_as_uint(f);
  u += 0x7fffu + ((u >> 16) & 1u);       // round-to-nearest-even
  return (unsigned short)(u >> 16);
}
__device__ __forceinline__ float bflo(unsigned u){ return __uint_as_float(u << 16); }
__device__ __forceinline__ float bfhi(unsigned u){ return __uint_as_float(u & 0xffff0000u); }

// ---------- 1. bucket histogram (bucket = dst >> 8), LDS-binned ----------
__global__ __launch_bounds__(256) void k_hist(const int* __restrict__ dst, int* __restrict__ bhist, int E, int NB){
  __shared__ int h[NBMAX];
  int t = threadIdx.x;
  for (int i = t; i < NBMAX; i += 256) h[i] = 0;
  __syncthreads();
  int t0 = blockIdx.x * 4096;
  #pragma unroll 4
  for (int k = 0; k < 16; ++k){
    int i = t0 + (k << 8) + t;
    if (i < E) atomicAdd(&h[dst[i] >> 8], 1);
  }
  __syncthreads();
  for (int b = t; b < NB; b += 256) if (h[b]) atomicAdd(&bhist[b], h[b]);
}

// ---------- 2. scan bucket sizes -> bases & cursors; off[N]=E ----------
__global__ __launch_bounds__(512) void k_bscan(const int* __restrict__ bhist, int* __restrict__ bbase,
                                               int* __restrict__ bcur, int* __restrict__ off, int NB, int N){
  __shared__ int sh[512];
  int t = threadIdx.x;
  int v = (t < NB) ? bhist[t] : 0;
  sh[t] = v; __syncthreads();
  for (int o = 1; o < 512; o <<= 1){
    int a = (t >= o) ? sh[t-o] : 0;
    __syncthreads();
    sh[t] += a;
    __syncthreads();
  }
  if (t < NB){ bbase[t] = sh[t] - v; bcur[t] = sh[t] - v; }
  if (t == 511) off[N] = sh[511];
}

// ---------- 3. partition edges into bucket-contiguous runs (LDS staged) ----------
__global__ __launch_bounds__(256) void k_part(const int* __restrict__ src, const int* __restrict__ dst,
    const float* __restrict__ w, int* __restrict__ bcur, int2* __restrict__ part, int E, int NB){
  __shared__ int2 stage[TPART];            // 64 KB
  __shared__ int hist[NBMAX];
  __shared__ int scn[NBMAX];
  __shared__ int cnt2[NBMAX];
  __shared__ int baseg[NBMAX];
  const int t = threadIdx.x;
  const int t0 = blockIdx.x * TPART;
  for (int i = t; i < NBMAX; i += 256){ hist[i] = 0; cnt2[i] = 0; }
  __syncthreads();
  // phase 1: histogram
  #pragma unroll 4
  for (int k = 0; k < 32; ++k){
    int i = t0 + (k << 8) + t;
    if (i < E) atomicAdd(&hist[dst[i] >> 8], 1);
  }
  __syncthreads();
  // phase 2: inclusive scan of hist (512-wide, 2 elems/thread)
  scn[t] = hist[t]; scn[t+256] = hist[t+256];
  __syncthreads();
  for (int o = 1; o < 512; o <<= 1){
    int a0 = (t >= o) ? scn[t-o] : 0;
    int a1 = scn[t+256-o];
    __syncthreads();
    scn[t] += a0; scn[t+256] += a1;
    __syncthreads();
  }
  // phase 3: reserve global runs
  for (int b = t; b < NB; b += 256) baseg[b] = hist[b] ? atomicAdd(&bcur[b], hist[b]) : 0;
  __syncthreads();
  // phase 4: stage records grouped by bucket
  #pragma unroll 4
  for (int k = 0; k < 32; ++k){
    int i = t0 + (k << 8) + t;
    if (i < E){
      int d = dst[i], b = d >> 8;
      int r = atomicAdd(&cnt2[b], 1);
      int pos = scn[b] - hist[b] + r;
      stage[pos] = make_int2(((d & 255) << 17) | src[i], __float_as_int(w[i]));
    }
  }
  __syncthreads();
  // phase 5: coalesced flush, one wave strides buckets
  int wv = t >> 6, ln = t & 63;
  for (int b = wv; b < NB; b += 4){
    int c = hist[b];
    if (!c) continue;
    int lo = scn[b] - c, gb = baseg[b];
    for (int s = ln; s < c; s += 64) part[gb + s] = stage[lo + s];
  }
}

// ---------- 4. exact fill per bucket: off[] + csr[] (L2-window-local) ----------
__global__ __launch_bounds__(256) void k_fill2(const int2* __restrict__ part, const int* __restrict__ bhist,
    const int* __restrict__ bbase, int* __restrict__ off, int2* __restrict__ csr, int N){
  __shared__ int deg[256], scn[256], c2[256];
  const int b = blockIdx.x, t = threadIdx.x;
  const int base = bbase[b], cnt = bhist[b];
  const int d0 = b << 8;
  const int nd = min(256, N - d0);
  deg[t] = 0; c2[t] = 0;
  __syncthreads();
  for (int s = t; s < cnt; s += 256) atomicAdd(&deg[(part[base+s].x >> 17) & 255], 1);
  __syncthreads();
  scn[t] = deg[t];
  __syncthreads();
  for (int o = 1; o < 256; o <<= 1){
    int a = (t >= o) ? scn[t-o] : 0;
    __syncthreads();
    scn[t] += a;
    __syncthreads();
  }
  if (t < nd) off[d0 + t] = base + scn[t] - deg[t];
  __syncthreads();
  for (int s = t; s < cnt; s += 256){
    int2 rec = part[base + s];
    int dl = (rec.x >> 17) & 255;
    int p = base + scn[dl] - deg[dl] + atomicAdd(&c2[dl], 1);
    csr[p] = make_int2(rec.x & 0x1FFFF, rec.y);
  }
}

// ---------- GEMM1: Y(bf16) = A @ W  (n x 128 @ 128 x 128) ----------
// 512 thr, tile 128 rows, micro 8x4. k-major LDS (b128 A-reads) + 8-deep W prefetch.
__global__ __launch_bounds__(512, 4) void k_gemm1(const float* __restrict__ A, const float* __restrict__ W,
                                                  unsigned short* __restrict__ Y, int n){
  __shared__ float As[128*LDA];            // As[k][row], 67.6 KB
  const int tid = threadIdx.x;
  const int r0 = blockIdx.x * 128;
  {
    int rr = tid >> 5;                 // 0..15
    const int k4 = (tid & 31) * 4;
    #pragma unroll
    for (int p = 0; p < 8; ++p, rr += 16){
      int rg = r0 + rr; if (rg > n-1) rg = n-1;
      float4 v = *(const float4*)(A + (size_t)rg*NF + k4);
      As[(k4+0)*LDA + rr] = v.x;       // 2-way write aliasing: free
      As[(k4+1)*LDA + rr] = v.y;
      As[(k4+2)*LDA + rr] = v.z;
      As[(k4+3)*LDA + rr] = v.w;
    }
  }
  __syncthreads();
  const int tx = tid & 31, ty = tid >> 5;   // tx: 32 col-groups, ty: 16 row-groups
  float acc[8][4] = {};
  float4 bw[8];
  #pragma unroll
  for (int u = 0; u < 8; ++u) bw[u] = *(const float4*)(W + u*NF + tx*4);
  for (int k0 = 0; k0 < 120; k0 += 8){
    #pragma unroll
    for (int u = 0; u < 8; ++u){
      const int k = k0 + u;
      float4 b = bw[u];
      bw[u] = *(const float4*)(W + (k+8)*NF + tx*4);      // prefetch 8 ahead
      const float* ar = As + k*LDA + ty*8;
      float4 a0 = *(const float4*)(ar);
      float4 a1 = *(const float4*)(ar + 4);
      acc[0][0]=fmaf(a0.x,b.x,acc[0][0]); acc[0][1]=fmaf(a0.x,b.y,acc[0][1]); acc[0][2]=fmaf(a0.x,b.z,acc[0][2]); acc[0][3]=fmaf(a0.x,b.w,acc[0][3]);
      acc[1][0]=fmaf(a0.y,b.x,acc[1][0]); acc[1][1]=fmaf(a0.y,b.y,acc[1][1]); acc[1][2]=fmaf(a0.y,b.z,acc[1][2]); acc[1][3]=fmaf(a0.y,b.w,acc[1][3]);
      acc[2][0]=fmaf(a0.z,b.x,acc[2][0]); acc[2][1]=fmaf(a0.z,b.y,acc[2][1]); acc[2][2]=fmaf(a0.z,b.z,acc[2][2]); acc[2][3]=fmaf(a0.z,b.w,acc[2][3]);
      acc[3][0]=fmaf(a0.w,b.x,acc[3][0]); acc[3][1]=fmaf(a0.w,b.y,acc[3][1]); acc[3][2]=fmaf(a0.w,b.z,acc[3][2]); acc[3][3]=fmaf(a0.w,b.w,acc[3][3]);
      acc[4][0]=fmaf(a1.x,b.x,acc[4][0]); acc[4][1]=fmaf(a1.x,b.y,acc[4][1]); acc[4][2]=fmaf(a1.x,b.z,acc[4][2]); acc[4][3]=fmaf(a1.x,b.w,acc[4][3]);
      acc[5][0]=fmaf(a1.y,b.x,acc[5][0]); acc[5][1]=fmaf(a1.y,b.y,acc[5][1]); acc[5][2]=fmaf(a1.y,b.z,acc[5][2]); acc[5][3]=fmaf(a1.y,b.w,acc[5][3]);
      acc[6][0]=fmaf(a1.z,b.x,acc[6][0]); acc[6][1]=fmaf(a1.z,b.y,acc[6][1]); acc[6][2]=fmaf(a1.z,b.z,acc[6][2]); acc[6][3]=fmaf(a1.z,b.w,acc[6][3]);
      acc[7][0]=fmaf(a1.w,b.x,acc[7][0]); acc[7][1]=fmaf(a1.w,b.y,acc[7][1]); acc[7][2]=fmaf(a1.w,b.z,acc[7][2]); acc[7][3]=fmaf(a1.w,b.w,acc[7][3]);
    }
  }
  #pragma unroll
  for (int u = 0; u < 8; ++u){              // peeled last batch, no prefetch
    const int k = 120 + u;
    float4 b = bw[u];
    const float* ar = As + k*LDA + ty*8;
    float4 a0 = *(const float4*)(ar);
    float4 a1 = *(const float4*)(ar + 4);
    acc[0][0]=fmaf(a0.x,b.x,acc[0][0]); acc[0][1]=fmaf(a0.x,b.y,acc[0][1]); acc[0][2]=fmaf(a0.x,b.z,acc[0][2]); acc[0][3]=fmaf(a0.x,b.w,acc[0][3]);
    acc[1][0]=fmaf(a0.y,b.x,acc[1][0]); acc[1][1]=fmaf(a0.y,b.y,acc[1][1]); acc[1][2]=fmaf(a0.y,b.z,acc[1][2]); acc[1][3]=fmaf(a0.y,b.w,acc[1][3]);
    acc[2][0]=fmaf(a0.z,b.x,acc[2][0]); acc[2][1]=fmaf(a0.z,b.y,acc[2][1]); acc[2][2]=fmaf(a0.z,b.z,acc[2][2]); acc[2][3]=fmaf(a0.z,b.w,acc[2][3]);
    acc[3][0]=fmaf(a0.w,b.x,acc[3][0]); acc[3][1]=fmaf(a0.w,b.y,acc[3][1]); acc[3][2]=fmaf(a0.w,b.z,acc[3][2]); acc[3][3]=fmaf(a0.w,b.w,acc[3][3]);
    acc[4][0]=fmaf(a1.x,b.x,acc[4][0]); acc[4][1]=fmaf(a1.x,b.y,acc[4][1]); acc[4][2]=fmaf(a1.x,b.z,acc[4][2]); acc[4][3]=fmaf(a1.x,b.w,acc[4][3]);
    acc[5][0]=fmaf(a1.y,b.x,acc[5][0]); acc[5][1]=fmaf(a1.y,b.y,acc[5][1]); acc[5][2]=fmaf(a1.y,b.z,acc[5][2]); acc[5][3]=fmaf(a1.y,b.w,acc[5][3]);
    acc[6][0]=fmaf(a1.z,b.x,acc[6][0]); acc[6][1]=fmaf(a1.z,b.y,acc[6][1]); acc[6][2]=fmaf(a1.z,b.z,acc[6][2]); acc[6][3]=fmaf(a1.z,b.w,acc[6][3]);
    acc[7][0]=fmaf(a1.w,b.x,acc[7][0]); acc[7][1]=fmaf(a1.w,b.y,acc[7][1]); acc[7][2]=fmaf(a1.w,b.z,acc[7][2]); acc[7][3]=fmaf(a1.w,b.w,acc[7][3]);
  }
  #pragma unroll
  for (int i = 0; i < 8; ++i){
    int rg = r0 + ty*8 + i;
    if (rg < n){
      uint2 p;
      p.x = (unsigned)f2bf(acc[i][0]) | ((unsigned)f2bf(acc[i][1]) << 16);
      p.y = (unsigned)f2bf(acc[i][2]) | ((unsigned)f2bf(acc[i][3]) << 16);
      *(uint2*)(Y + (size_t)rg*NF + tx*4) = p;
    }
  }
}

// ---------- GEMM2: G(bf16) = H @ W1  (n x 128 @ 128 x 64), micro 4x4 ----------
__global__ __launch_bounds__(512, 4) void k_gemm2(const float* __restrict__ A, const float* __restrict__ W,
                                                  unsigned short* __restrict__ G, int n){
  __shared__ float As[128*LDA];
  const int tid = threadIdx.x;
  const int r0 = blockIdx.x * 128;
  {
    int rr = tid >> 5;
    const int k4 = (tid & 31) * 4;
    #pragma unroll
    for (int p = 0; p < 8; ++p, rr += 16){
      int rg = r0 + rr; if (rg > n-1) rg = n-1;
      float4 v = *(const float4*)(A + (size_t)rg*NF + k4);
      As[(k4+0)*LDA + rr] = v.x;
      As[(k4+1)*LDA + rr] = v.y;
      As[(k4+2)*LDA + rr] = v.z;
      As[(k4+3)*LDA + rr] = v.w;
    }
  }
  __syncthreads();
  const int tx = tid & 15, ty = tid >> 4;   // tx: 16 col-groups, ty: 32 row-groups
  float acc[4][4] = {};
  float4 bw[8];
  #pragma unroll
  for (int u = 0; u < 8; ++u) bw[u] = *(const float4*)(W + u*NC + tx*4);
  for (int k0 = 0; k0 < 120; k0 += 8){
    #pragma unroll
    for (int u = 0; u < 8; ++u){
      const int k = k0 + u;
      float4 b = bw[u];
      bw[u] = *(const float4*)(W + (k+8)*NC + tx*4);
      float4 a = *(const float4*)(As + k*LDA + ty*4);
      acc[0][0]=fmaf(a.x,b.x,acc[0][0]); acc[0][1]=fmaf(a.x,b.y,acc[0][1]); acc[0][2]=fmaf(a.x,b.z,acc[0][2]); acc[0][3]=fmaf(a.x,b.w,acc[0][3]);
      acc[1][0]=fmaf(a.y,b.x,acc[1][0]); acc[1][1]=fmaf(a.y,b.y,acc[1][1]); acc[1][2]=fmaf(a.y,b.z,acc[1][2]); acc[1][3]=fmaf(a.y,b.w,acc[1][3]);
      acc[2][0]=fmaf(a.z,b.x,acc[2][0]); acc[2][1]=fmaf(a.z,b.y,acc[2][1]); acc[2][2]=fmaf(a.z,b.z,acc[2][2]); acc[2][3]=fmaf(a.z,b.w,acc[2][3]);
      acc[3][0]=fmaf(a.w,b.x,acc[3][0]); acc[3][1]=fmaf(a.w,b.y,acc[3][1]); acc[3][2]=fmaf(a.w,b.z,acc[3][2]); acc[3][3]=fmaf(a.w,b.w,acc[3][3]);
    }
  }
  #pragma unroll
  for (int u = 0; u < 8; ++u){
    const int k = 120 + u;
    float4 b = bw[u];
    float4 a = *(const float4*)(As + k*LDA + ty*4);
    acc[0][0]=fmaf(a.x,b.x,acc[0][0]); acc[0][1]=fmaf(a.x,b.y,acc[0][1]); acc[0][2]=fmaf(a.x,b.z,acc[0][2]); acc[0][3]=fmaf(a.x,b.w,acc[0][3]);
    acc[1][0]=fmaf(a.y,b.x,acc[1][0]); acc[1][1]=fmaf(a.y,b.y,acc[1][1]); acc[1][2]=fmaf(a.y,b.z,acc[1][2]); acc[1][3]=fmaf(a.y,b.w,acc[1][3]);
    acc[2][0]=fmaf(a.z,b.x,acc[2][0]); acc[2][1]=fmaf(a.z,b.y,acc[2][1]); acc[2][2]=fmaf(a.z,b.z,acc[2][2]); acc[2][3]=fmaf(a.z,b.w,acc[2][3]);
    acc[3][0]=fmaf(a.w,b.x,acc[3][0]); acc[3][1]=fmaf(a.w,b.y,acc[3][1]); acc[3][2]=fmaf(a.w,b.z,acc[3][2]); acc[3][3]=fmaf(a.w,b.w,acc[3][3]);
  }
  #pragma unroll
  for (int i = 0; i < 4; ++i){
    int rg = r0 + ty*4 + i;
    if (rg < n){
      uint2 p;
      p.x = (unsigned)f2bf(acc[i][0]) | ((unsigned)f2bf(acc[i][1]) << 16);
      p.y = (unsigned)f2bf(acc[i][2]) | ((unsigned)f2bf(acc[i][3]) << 16);
      *(uint2*)(G + (size_t)rg*NC + tx*4) = p;
    }
  }
}

// ---------- SpMM1 + bias + ReLU: h = relu(A@y + b0); y bf16, scalar edge walk ----------
__global__ __launch_bounds__(256) void k_spmm_relu(const unsigned short* __restrict__ y, const int2* __restrict__ csr,
    const int* __restrict__ off, const float* __restrict__ bias, float* __restrict__ h, int n){
  int wid  = (blockIdx.x * 256 + threadIdx.x) >> 6;
  int lane = threadIdx.x & 63;
  if (wid >= n) return;
  const int s = __builtin_amdgcn_readfirstlane(off[wid]);
  const int e = __builtin_amdgcn_readfirstlane(off[wid+1]);
  float ax[8], ay[8];
  #pragma unroll
  for (int k = 0; k < 8; ++k){ ax[k] = 0.f; ay[k] = 0.f; }
  for (int j = s; j < e; j += 8){
    int  sk[8];  float wk[8];
    #pragma unroll
    for (int k = 0; k < 8; ++k){
      int id = j + k; if (id > e-1) id = e-1;           // scalar clamp
      int2 ed = csr[id];                                // uniform address
      sk[k] = __builtin_amdgcn_readfirstlane(ed.x);     // SGPR row index
      int wbits = __builtin_amdgcn_readfirstlane(ed.y);
      wk[k] = (j + k < e) ? __int_as_float(wbits) : 0.f; // scalar select
    }
    unsigned v[8];
    #pragma unroll
    for (int k = 0; k < 8; ++k)
      v[k] = ((const unsigned*)(y + (size_t)sk[k] * NF))[lane];  // saddr gather, 256B/row
    #pragma unroll
    for (int k = 0; k < 8; ++k){
      ax[k] = fmaf(wk[k], bflo(v[k]), ax[k]);
      ay[k] = fmaf(wk[k], bfhi(v[k]), ay[k]);
    }
  }
  float sx = ((ax[0]+ax[1]) + (ax[2]+ax[3])) + ((ax[4]+ax[5]) + (ax[6]+ax[7]));
  float sy = ((ay[0]+ay[1]) + (ay[2]+ay[3])) + ((ay[4]+ay[5]) + (ay[6]+ay[7]));
  float2 bb = ((const float2*)bias)[lane];
  ((float2*)(h + (size_t)wid * NF))[lane] = make_float2(fmaxf(sx+bb.x, 0.f), fmaxf(sy+bb.y, 0.f));
}

// ---------- SpMM2 + bias + log_softmax: out = ls(A@g + b1); g bf16, lane==class ----------
__global__ __launch_bounds__(256) void k_spmm_ls(const unsigned short* __restrict__ g, const int2* __restrict__ csr,
    const int* __restrict__ off, const float* __restrict__ bias, float* __restrict__ out, int n){
  int wid  = (blockIdx.x * 256 + threadIdx.x) >> 6;
  int lane = threadIdx.x & 63;
  if (wid >= n) return;
  const int s = __builtin_amdgcn_readfirstlane(off[wid]);
  const int e = __builtin_amdgcn_readfirstlane(off[wid+1]);
  float z[8];
  #pragma unroll
  for (int k = 0; k < 8; ++k) z[k] = 0.f;
  for (int j = s; j < e; j += 8){
    int  sk[8];  float wk[8];
    #pragma unroll
    for (int k = 0; k < 8; ++k){
      int id = j + k; if (id > e-1) id = e-1;
      int2 ed = csr[id];
      sk[k] = __builtin_amdgcn_readfirstlane(ed.x);
      int wbits = __builtin_amdgcn_readfirstlane(ed.y);
      wk[k] = (j + k < e) ? __int_as_float(wbits) : 0.f;
    }
    unsigned short v[8];
    #pragma unroll
    for (int k = 0; k < 8; ++k)
      v[k] = (g + (size_t)sk[k] * NC)[lane];            // saddr gather, 128B/row
    #pragma unroll
    for (int k = 0; k < 8; ++k)
      z[k] = fmaf(wk[k], bflo((unsigned)v[k]), z[k]);
  }
  float zz = ((z[0]+z[1]) + (z[2]+z[3])) + ((z[4]+z[5]) + (z[6]+z[7]));
  zz += bias[lane];
  float m = zz;
  for (int o = 32; o; o >>= 1) m = fmaxf(m, __shfl_xor(m, o));
  float sum = expf(zz - m);
  for (int o = 32; o; o >>= 1) sum += __shfl_xor(sum, o);
  out[(size_t)wid * NC + lane] = zz - m - logf(sum);
}

extern "C" void kernel_launch(void* const* d_in, const int* in_sizes, int n_in,
                              void* d_out, int out_size, void* d_ws, size_t ws_size,
                              hipStream_t stream){
  const float* x  = (const float*)d_in[0];
  const int* esrc = (const int*)d_in[1];
  const int* edst = (const int*)d_in[2];
  const float* ew = (const float*)d_in[3];
  const float* W0 = (const float*)d_in[4];
  const float* b0 = (const float*)d_in[5];
  const float* W1 = (const float*)d_in[6];
  const float* b1 = (const float*)d_in[7];
  float* out = (float*)d_out;

  const int N = in_sizes[0] / NF;
  const int E = in_sizes[1];
  const int NB = (N + 255) >> 8;            // 391 buckets of 256 dsts

  char* ws = (char*)d_ws;
  size_t o = 0;
  int*  bhist = (int*) (ws + o); o = alignup(o + NBMAX*4);
  int*  bbase = (int*) (ws + o); o = alignup(o + NBMAX*4);
  int*  bcur  = (int*) (ws + o); o = alignup(o + NBMAX*4);
  int*  off   = (int*) (ws + o); o = alignup(o + (size_t)(N+1)*4);
  int2* part  = (int2*)(ws + o); o = alignup(o + (size_t)E*8);
  int2* csr   = (int2*)(ws + o); o = alignup(o + (size_t)E*8);
  unsigned short* y = (unsigned short*)(ws + o); o = alignup(o + (size_t)N*NF*2);  // bf16; reused as g
  float* h    = (float*)(ws + o); o = alignup(o + (size_t)N*NF*4);
  unsigned short* g = y;  // y dead after k_spmm_relu

  hipMemsetAsync(bhist, 0, NBMAX*4, stream);

  const int hb = (E + 4095)/4096;
  const int pb = (E + TPART-1)/TPART;

  k_hist <<<hb, 256, 0, stream>>>(edst, bhist, E, NB);
  k_bscan<<<1, 512, 0, stream>>>(bhist, bbase, bcur, off, NB, N);
  k_part <<<pb, 256, 0, stream>>>(esrc, edst, ew, bcur, part, E, NB);
  k_fill2<<<NB, 256, 0, stream>>>(part, bhist, bbase, off, csr, N);

  const int gb = (N + 127)/128;
  const int sb = (N + 3)/4;

  k_gemm1<<<gb, 512, 0, stream>>>(x, W0, y, N);               // y = bf16(x @ W0)
  k_spmm_relu<<<sb, 256, 0, stream>>>(y, csr, off, b0, h, N); // h = relu(A y + b0)
  k_gemm2<<<gb, 512, 0, stream>>>(h, W1, g, N);               // g = bf16(h @ W1)
  k_spmm_ls<<<sb, 256, 0, stream>>>(g, csr, off, b1, out, N); // out = log_softmax(A g + b1)
}

// Round 9
// 231.399 us; speedup vs baseline: 1.4526x; 1.4526x over previous
//
#include <hip/hip_runtime.h>

#define NF 128
#define NC 64
#define NBMAX 512          // max dst-buckets (N/256 = 391 for N=100000)
#define TPART 8192         // edges per k_part block
#define WPITCH 136         // LDS W^T pitch in bf16: 272B rows -> 16B aligned, 2-way banks (free)

static inline size_t alignup(size_t x){ return (x + 255) & ~(size_t)255; }

typedef __attribute__((ext_vector_type(8))) short bf16x8;
typedef __attribute__((ext_vector_type(4))) float f32x4;

__device__ __forceinline__ unsigned short f2bf(float f){
  unsigned u = __float_as_uint(f);
  u += 0x7fffu + ((u >> 16) & 1u);       // round-to-nearest-even
  return (unsigned short)(u >> 16);
}
__device__ __forceinline__ float bflo(unsigned u){ return __uint_as_float(u << 16); }
__device__ __forceinline__ float bfhi(unsigned u){ return __uint_as_float(u & 0xffff0000u); }

// ---------- 1. bucket histogram (bucket = dst >> 8), LDS-binned ----------
__global__ __launch_bounds__(256) void k_hist(const int* __restrict__ dst, int* __restrict__ bhist, int E, int NB){
  __shared__ int h[NBMAX];
  int t = threadIdx.x;
  for (int i = t; i < NBMAX; i += 256) h[i] = 0;
  __syncthreads();
  int t0 = blockIdx.x * 4096;
  #pragma unroll 4
  for (int k = 0; k < 16; ++k){
    int i = t0 + (k << 8) + t;
    if (i < E) atomicAdd(&h[dst[i] >> 8], 1);
  }
  __syncthreads();
  for (int b = t; b < NB; b += 256) if (h[b]) atomicAdd(&bhist[b], h[b]);
}

// ---------- 2. scan bucket sizes -> bases & cursors; off[N]=E ----------
__global__ __launch_bounds__(512) void k_bscan(const int* __restrict__ bhist, int* __restrict__ bbase,
                                               int* __restrict__ bcur, int* __restrict__ off, int NB, int N){
  __shared__ int sh[512];
  int t = threadIdx.x;
  int v = (t < NB) ? bhist[t] : 0;
  sh[t] = v; __syncthreads();
  for (int o = 1; o < 512; o <<= 1){
    int a = (t >= o) ? sh[t-o] : 0;
    __syncthreads();
    sh[t] += a;
    __syncthreads();
  }
  if (t < NB){ bbase[t] = sh[t] - v; bcur[t] = sh[t] - v; }
  if (t == 511) off[N] = sh[511];
}

// ---------- 3. partition edges into bucket-contiguous runs (LDS staged) ----------
__global__ __launch_bounds__(256) void k_part(const int* __restrict__ src, const int* __restrict__ dst,
    const float* __restrict__ w, int* __restrict__ bcur, int2* __restrict__ part, int E, int NB){
  __shared__ int2 stage[TPART];            // 64 KB
  __shared__ int hist[NBMAX];
  __shared__ int scn[NBMAX];
  __shared__ int cnt2[NBMAX];
  __shared__ int baseg[NBMAX];
  const int t = threadIdx.x;
  const int t0 = blockIdx.x * TPART;
  for (int i = t; i < NBMAX; i += 256){ hist[i] = 0; cnt2[i] = 0; }
  __syncthreads();
  // phase 1: histogram
  #pragma unroll 4
  for (int k = 0; k < 32; ++k){
    int i = t0 + (k << 8) + t;
    if (i < E) atomicAdd(&hist[dst[i] >> 8], 1);
  }
  __syncthreads();
  // phase 2: inclusive scan of hist (512-wide, 2 elems/thread)
  scn[t] = hist[t]; scn[t+256] = hist[t+256];
  __syncthreads();
  for (int o = 1; o < 512; o <<= 1){
    int a0 = (t >= o) ? scn[t-o] : 0;
    int a1 = scn[t+256-o];
    __syncthreads();
    scn[t] += a0; scn[t+256] += a1;
    __syncthreads();
  }
  // phase 3: reserve global runs
  for (int b = t; b < NB; b += 256) baseg[b] = hist[b] ? atomicAdd(&bcur[b], hist[b]) : 0;
  __syncthreads();
  // phase 4: stage records grouped by bucket
  #pragma unroll 4
  for (int k = 0; k < 32; ++k){
    int i = t0 + (k << 8) + t;
    if (i < E){
      int d = dst[i], b = d >> 8;
      int r = atomicAdd(&cnt2[b], 1);
      int pos = scn[b] - hist[b] + r;
      stage[pos] = make_int2(((d & 255) << 17) | src[i], __float_as_int(w[i]));
    }
  }
  __syncthreads();
  // phase 5: coalesced flush, one wave strides buckets
  int wv = t >> 6, ln = t & 63;
  for (int b = wv; b < NB; b += 4){
    int c = hist[b];
    if (!c) continue;
    int lo = scn[b] - c, gb = baseg[b];
    for (int s = ln; s < c; s += 64) part[gb + s] = stage[lo + s];
  }
}

// ---------- 4. exact fill per bucket: off[] + csr[] (L2-window-local) ----------
__global__ __launch_bounds__(256) void k_fill2(const int2* __restrict__ part, const int* __restrict__ bhist,
    const int* __restrict__ bbase, int* __restrict__ off, int2* __restrict__ csr, int N){
  __shared__ int deg[256], scn[256], c2[256];
  const int b = blockIdx.x, t = threadIdx.x;
  const int base = bbase[b], cnt = bhist[b];
  const int d0 = b << 8;
  const int nd = min(256, N - d0);
  deg[t] = 0; c2[t] = 0;
  __syncthreads();
  for (int s = t; s < cnt; s += 256) atomicAdd(&deg[(part[base+s].x >> 17) & 255], 1);
  __syncthreads();
  scn[t] = deg[t];
  __syncthreads();
  for (int o = 1; o < 256; o <<= 1){
    int a = (t >= o) ? scn[t-o] : 0;
    __syncthreads();
    scn[t] += a;
    __syncthreads();
  }
  if (t < nd) off[d0 + t] = base + scn[t] - deg[t];
  __syncthreads();
  for (int s = t; s < cnt; s += 256){
    int2 rec = part[base + s];
    int dl = (rec.x >> 17) & 255;
    int p = base + scn[dl] - deg[dl] + atomicAdd(&c2[dl], 1);
    csr[p] = make_int2(rec.x & 0x1FFFF, rec.y);
  }
}

// ---------- GEMM1 (MFMA): Y(bf16) = x(f32) @ W0  (n x 128 @ 128 x 128) ----------
// 4 waves/block, each wave owns a 16-row strip x full 128 cols.
// W0 staged once/block into LDS transposed bf16 (Wt[c][k], pitch 136).
// A-frag: 32B f32 per lane from x, converted in-register.
__global__ __launch_bounds__(256) void k_gemm1(const float* __restrict__ A, const float* __restrict__ W,
                                               unsigned short* __restrict__ Y, int n){
  __shared__ unsigned short Wt[128*WPITCH];    // 34.8 KB
  const int tid = threadIdx.x;
  for (int idx = tid; idx < 128*128; idx += 256){
    int k = idx >> 7, c = idx & 127;
    Wt[c*WPITCH + k] = f2bf(W[idx]);
  }
  __syncthreads();
  const int lane = tid & 63, wv = tid >> 6;
  const int r0 = blockIdx.x*64 + wv*16;
  int rA = r0 + (lane & 15); if (rA > n-1) rA = n-1;
  const int kq = (lane >> 4) << 3;             // 0,8,16,24
  f32x4 acc[8] = {};
  #pragma unroll
  for (int kk = 0; kk < 4; ++kk){
    const float* ap = A + (size_t)rA*NF + kk*32 + kq;
    float4 a0 = *(const float4*)ap;
    float4 a1 = *(const float4*)(ap + 4);
    bf16x8 af;
    af[0]=(short)f2bf(a0.x); af[1]=(short)f2bf(a0.y); af[2]=(short)f2bf(a0.z); af[3]=(short)f2bf(a0.w);
    af[4]=(short)f2bf(a1.x); af[5]=(short)f2bf(a1.y); af[6]=(short)f2bf(a1.z); af[7]=(short)f2bf(a1.w);
    const unsigned short* wp = Wt + (lane & 15)*WPITCH + kk*32 + kq;
    #pragma unroll
    for (int nt = 0; nt < 8; ++nt){
      bf16x8 bf = *(const bf16x8*)(wp + nt*16*WPITCH);
      acc[nt] = __builtin_amdgcn_mfma_f32_16x16x32_bf16(af, bf, acc[nt], 0, 0, 0);
    }
  }
  // D: col = nt*16 + (lane&15), row = r0 + (lane>>4)*4 + j   [m89 mapping]
  const int rb = r0 + ((lane >> 4) << 2);
  #pragma unroll
  for (int j = 0; j < 4; ++j){
    int rg = rb + j;
    if (rg < n){
      unsigned short* yp = Y + (size_t)rg*NF + (lane & 15);
      #pragma unroll
      for (int nt = 0; nt < 8; ++nt) yp[nt*16] = f2bf(acc[nt][j]);
    }
  }
}

// ---------- GEMM2 (MFMA): G(bf16) = h(bf16) @ W1  (n x 128 @ 128 x 64) ----------
__global__ __launch_bounds__(256) void k_gemm2(const unsigned short* __restrict__ Ab, const float* __restrict__ W,
                                               unsigned short* __restrict__ G, int n){
  __shared__ unsigned short Wt[64*WPITCH];     // 17.4 KB
  const int tid = threadIdx.x;
  for (int idx = tid; idx < 128*64; idx += 256){
    int k = idx >> 6, c = idx & 63;
    Wt[c*WPITCH + k] = f2bf(W[idx]);
  }
  __syncthreads();
  const int lane = tid & 63, wv = tid >> 6;
  const int r0 = blockIdx.x*64 + wv*16;
  int rA = r0 + (lane & 15); if (rA > n-1) rA = n-1;
  const int kq = (lane >> 4) << 3;
  f32x4 acc[4] = {};
  #pragma unroll
  for (int kk = 0; kk < 4; ++kk){
    bf16x8 af = *(const bf16x8*)(Ab + (size_t)rA*NF + kk*32 + kq);
    const unsigned short* wp = Wt + (lane & 15)*WPITCH + kk*32 + kq;
    #pragma unroll
    for (int nt = 0; nt < 4; ++nt){
      bf16x8 bf = *(const bf16x8*)(wp + nt*16*WPITCH);
      acc[nt] = __builtin_amdgcn_mfma_f32_16x16x32_bf16(af, bf, acc[nt], 0, 0, 0);
    }
  }
  const int rb = r0 + ((lane >> 4) << 2);
  #pragma unroll
  for (int j = 0; j < 4; ++j){
    int rg = rb + j;
    if (rg < n){
      unsigned short* gp = G + (size_t)rg*NC + (lane & 15);
      #pragma unroll
      for (int nt = 0; nt < 4; ++nt) gp[nt*16] = f2bf(acc[nt][j]);
    }
  }
}

// ---------- SpMM1 + bias + ReLU: h(bf16) = relu(A@y + b0); scalar edge walk ----------
__global__ __launch_bounds__(256) void k_spmm_relu(const unsigned short* __restrict__ y, const int2* __restrict__ csr,
    const int* __restrict__ off, const float* __restrict__ bias, unsigned short* __restrict__ h, int n){
  int wid  = (blockIdx.x * 256 + threadIdx.x) >> 6;
  int lane = threadIdx.x & 63;
  if (wid >= n) return;
  const int s = __builtin_amdgcn_readfirstlane(off[wid]);
  const int e = __builtin_amdgcn_readfirstlane(off[wid+1]);
  float ax[8], ay[8];
  #pragma unroll
  for (int k = 0; k < 8; ++k){ ax[k] = 0.f; ay[k] = 0.f; }
  for (int j = s; j < e; j += 8){
    int  sk[8];  float wk[8];
    #pragma unroll
    for (int k = 0; k < 8; ++k){
      int id = j + k; if (id > e-1) id = e-1;           // scalar clamp
      int2 ed = csr[id];                                // uniform address
      sk[k] = __builtin_amdgcn_readfirstlane(ed.x);     // SGPR row index
      int wbits = __builtin_amdgcn_readfirstlane(ed.y);
      wk[k] = (j + k < e) ? __int_as_float(wbits) : 0.f; // scalar select
    }
    unsigned v[8];
    #pragma unroll
    for (int k = 0; k < 8; ++k)
      v[k] = ((const unsigned*)(y + (size_t)sk[k] * NF))[lane];  // saddr gather, 256B/row
    #pragma unroll
    for (int k = 0; k < 8; ++k){
      ax[k] = fmaf(wk[k], bflo(v[k]), ax[k]);
      ay[k] = fmaf(wk[k], bfhi(v[k]), ay[k]);
    }
  }
  float sx = ((ax[0]+ax[1]) + (ax[2]+ax[3])) + ((ax[4]+ax[5]) + (ax[6]+ax[7]));
  float sy = ((ay[0]+ay[1]) + (ay[2]+ay[3])) + ((ay[4]+ay[5]) + (ay[6]+ay[7]));
  float2 bb = ((const float2*)bias)[lane];
  sx = fmaxf(sx + bb.x, 0.f);
  sy = fmaxf(sy + bb.y, 0.f);
  unsigned hv = (unsigned)f2bf(sx) | ((unsigned)f2bf(sy) << 16);
  *(unsigned*)(h + (size_t)wid * NF + lane*2) = hv;     // packed bf16 pair
}

// ---------- SpMM2 + bias + log_softmax: out = ls(A@g + b1); g bf16, lane==class ----------
__global__ __launch_bounds__(256) void k_spmm_ls(const unsigned short* __restrict__ g, const int2* __restrict__ csr,
    const int* __restrict__ off, const float* __restrict__ bias, float* __restrict__ out, int n){
  int wid  = (blockIdx.x * 256 + threadIdx.x) >> 6;
  int lane = threadIdx.x & 63;
  if (wid >= n) return;
  const int s = __builtin_amdgcn_readfirstlane(off[wid]);
  const int e = __builtin_amdgcn_readfirstlane(off[wid+1]);
  float z[8];
  #pragma unroll
  for (int k = 0; k < 8; ++k) z[k] = 0.f;
  for (int j = s; j < e; j += 8){
    int  sk[8];  float wk[8];
    #pragma unroll
    for (int k = 0; k < 8; ++k){
      int id = j + k; if (id > e-1) id = e-1;
      int2 ed = csr[id];
      sk[k] = __builtin_amdgcn_readfirstlane(ed.x);
      int wbits = __builtin_amdgcn_readfirstlane(ed.y);
      wk[k] = (j + k < e) ? __int_as_float(wbits) : 0.f;
    }
    unsigned short v[8];
    #pragma unroll
    for (int k = 0; k < 8; ++k)
      v[k] = (g + (size_t)sk[k] * NC)[lane];            // saddr gather, 128B/row
    #pragma unroll
    for (int k = 0; k < 8; ++k)
      z[k] = fmaf(wk[k], bflo((unsigned)v[k]), z[k]);
  }
  float zz = ((z[0]+z[1]) + (z[2]+z[3])) + ((z[4]+z[5]) + (z[6]+z[7]));
  zz += bias[lane];
  float m = zz;
  for (int o = 32; o; o >>= 1) m = fmaxf(m, __shfl_xor(m, o));
  float sum = expf(zz - m);
  for (int o = 32; o; o >>= 1) sum += __shfl_xor(sum, o);
  out[(size_t)wid * NC + lane] = zz - m - logf(sum);
}

extern "C" void kernel_launch(void* const* d_in, const int* in_sizes, int n_in,
                              void* d_out, int out_size, void* d_ws, size_t ws_size,
                              hipStream_t stream){
  const float* x  = (const float*)d_in[0];
  const int* esrc = (const int*)d_in[1];
  const int* edst = (const int*)d_in[2];
  const float* ew = (const float*)d_in[3];
  const float* W0 = (const float*)d_in[4];
  const float* b0 = (const float*)d_in[5];
  const float* W1 = (const float*)d_in[6];
  const float* b1 = (const float*)d_in[7];
  float* out = (float*)d_out;

  const int N = in_sizes[0] / NF;
  const int E = in_sizes[1];
  const int NB = (N + 255) >> 8;            // 391 buckets of 256 dsts

  char* ws = (char*)d_ws;
  size_t o = 0;
  int*  bhist = (int*) (ws + o); o = alignup(o + NBMAX*4);
  int*  bbase = (int*) (ws + o); o = alignup(o + NBMAX*4);
  int*  bcur  = (int*) (ws + o); o = alignup(o + NBMAX*4);
  int*  off   = (int*) (ws + o); o = alignup(o + (size_t)(N+1)*4);
  int2* part  = (int2*)(ws + o); o = alignup(o + (size_t)E*8);
  int2* csr   = (int2*)(ws + o); o = alignup(o + (size_t)E*8);
  unsigned short* y  = (unsigned short*)(ws + o); o = alignup(o + (size_t)N*NF*2);  // bf16; reused as g
  unsigned short* hb = (unsigned short*)(ws + o); o = alignup(o + (size_t)N*NF*2);  // bf16 h
  unsigned short* g = y;  // y dead after k_spmm_relu

  hipMemsetAsync(bhist, 0, NBMAX*4, stream);

  const int hbk = (E + 4095)/4096;
  const int pb = (E + TPART-1)/TPART;

  k_hist <<<hbk, 256, 0, stream>>>(edst, bhist, E, NB);
  k_bscan<<<1, 512, 0, stream>>>(bhist, bbase, bcur, off, NB, N);
  k_part <<<pb, 256, 0, stream>>>(esrc, edst, ew, bcur, part, E, NB);
  k_fill2<<<NB, 256, 0, stream>>>(part, bhist, bbase, off, csr, N);

  const int gb = (N + 63)/64;               // 4 waves x 16 rows per block
  const int sb = (N + 3)/4;

  k_gemm1<<<gb, 256, 0, stream>>>(x, W0, y, N);                // y = bf16(x @ W0)   [MFMA]
  k_spmm_relu<<<sb, 256, 0, stream>>>(y, csr, off, b0, hb, N); // hb = bf16(relu(A y + b0))
  k_gemm2<<<gb, 256, 0, stream>>>(hb, W1, g, N);               // g = bf16(hb @ W1)  [MFMA]
  k_spmm_ls<<<sb, 256, 0, stream>>>(g, csr, off, b1, out, N);  // out = log_softmax(A g + b1)
}

// Round 10
// 223.153 us; speedup vs baseline: 1.5063x; 1.0370x over previous
//
#include <hip/hip_runtime.h>

#define NF 128
#define NC 64
#define NBMAX 512          // max dst-buckets (N/256 = 391 for N=100000)
#define TPART 8192         // edges per k_part block
#define WPITCH 136         // LDS W^T pitch in bf16: 272B rows, 2-way banks (free)

static inline size_t alignup(size_t x){ return (x + 255) & ~(size_t)255; }

typedef __attribute__((ext_vector_type(8))) short bf16x8;
typedef __attribute__((ext_vector_type(4))) float f32x4;
typedef __attribute__((ext_vector_type(16))) int i32x16;

__device__ __forceinline__ unsigned short f2bf(float f){
  unsigned u = __float_as_uint(f);
  u += 0x7fffu + ((u >> 16) & 1u);       // round-to-nearest-even
  return (unsigned short)(u >> 16);
}
__device__ __forceinline__ float bflo(unsigned u){ return __uint_as_float(u << 16); }
__device__ __forceinline__ float bfhi(unsigned u){ return __uint_as_float(u & 0xffff0000u); }

// 8 edge records in one scalar load (wave-uniform 64B-aligned address)
__device__ __forceinline__ i32x16 sload16(const int2* p){
  i32x16 r;
  asm volatile("s_load_dwordx16 %0, %1, 0x0\n\ts_waitcnt lgkmcnt(0)"
               : "=&s"(r) : "s"(p));
  return r;
}

// ---------- 1. bucket histogram (bucket = dst >> 8), LDS-binned ----------
__global__ __launch_bounds__(256) void k_hist(const int* __restrict__ dst, int* __restrict__ bhist, int E, int NB){
  __shared__ int h[NBMAX];
  int t = threadIdx.x;
  for (int i = t; i < NBMAX; i += 256) h[i] = 0;
  __syncthreads();
  int t0 = blockIdx.x * 4096;
  #pragma unroll 4
  for (int k = 0; k < 16; ++k){
    int i = t0 + (k << 8) + t;
    if (i < E) atomicAdd(&h[dst[i] >> 8], 1);
  }
  __syncthreads();
  for (int b = t; b < NB; b += 256) if (h[b]) atomicAdd(&bhist[b], h[b]);
}

// ---------- 2. scan bucket sizes -> bases & cursors; off[N]=E ----------
__global__ __launch_bounds__(512) void k_bscan(const int* __restrict__ bhist, int* __restrict__ bbase,
                                               int* __restrict__ bcur, int* __restrict__ off, int NB, int N){
  __shared__ int sh[512];
  int t = threadIdx.x;
  int v = (t < NB) ? bhist[t] : 0;
  sh[t] = v; __syncthreads();
  for (int o = 1; o < 512; o <<= 1){
    int a = (t >= o) ? sh[t-o] : 0;
    __syncthreads();
    sh[t] += a;
    __syncthreads();
  }
  if (t < NB){ bbase[t] = sh[t] - v; bcur[t] = sh[t] - v; }
  if (t == 511) off[N] = sh[511];
}

// ---------- 3. partition edges into bucket-contiguous runs (512 thr) ----------
__global__ __launch_bounds__(512) void k_part(const int* __restrict__ src, const int* __restrict__ dst,
    const float* __restrict__ w, int* __restrict__ bcur, int2* __restrict__ part, int E, int NB){
  __shared__ int2 stage[TPART];            // 64 KB
  __shared__ int hist[NBMAX];
  __shared__ int scn[NBMAX];
  __shared__ int cnt2[NBMAX];
  __shared__ int baseg[NBMAX];
  const int t = threadIdx.x;
  const int t0 = blockIdx.x * TPART;
  hist[t] = 0; cnt2[t] = 0;
  __syncthreads();
  // phase 1: histogram (16 iters)
  #pragma unroll 4
  for (int k = 0; k < 16; ++k){
    int i = t0 + (k << 9) + t;
    if (i < E) atomicAdd(&hist[dst[i] >> 8], 1);
  }
  __syncthreads();
  // phase 2: inclusive scan, 1 elem/thread
  scn[t] = hist[t];
  __syncthreads();
  for (int o = 1; o < 512; o <<= 1){
    int a = (t >= o) ? scn[t-o] : 0;
    __syncthreads();
    scn[t] += a;
    __syncthreads();
  }
  // phase 3: reserve global runs
  if (t < NB) baseg[t] = hist[t] ? atomicAdd(&bcur[t], hist[t]) : 0;
  __syncthreads();
  // phase 4: stage records grouped by bucket (16 iters)
  #pragma unroll 4
  for (int k = 0; k < 16; ++k){
    int i = t0 + (k << 9) + t;
    if (i < E){
      int d = dst[i], b = d >> 8;
      int r = atomicAdd(&cnt2[b], 1);
      stage[scn[b] - hist[b] + r] = make_int2(((d & 255) << 17) | src[i], __float_as_int(w[i]));
    }
  }
  __syncthreads();
  // phase 5: coalesced flush, 8 waves stride buckets
  int wv = t >> 6, ln = t & 63;
  for (int b = wv; b < NB; b += 8){
    int c = hist[b];
    if (!c) continue;
    int lo = scn[b] - c, gb = baseg[b];
    for (int s2 = ln; s2 < c; s2 += 64) part[gb + s2] = stage[lo + s2];
  }
}

// ---------- 4. exact fill per bucket: off[] + csr[] (L2-window-local) ----------
__global__ __launch_bounds__(256) void k_fill2(const int2* __restrict__ part, const int* __restrict__ bhist,
    const int* __restrict__ bbase, int* __restrict__ off, int2* __restrict__ csr, int N){
  __shared__ int deg[256], scn[256], c2[256];
  const int b = blockIdx.x, t = threadIdx.x;
  const int base = bbase[b], cnt = bhist[b];
  const int d0 = b << 8;
  const int nd = min(256, N - d0);
  deg[t] = 0; c2[t] = 0;
  __syncthreads();
  for (int s = t; s < cnt; s += 256) atomicAdd(&deg[(part[base+s].x >> 17) & 255], 1);
  __syncthreads();
  scn[t] = deg[t];
  __syncthreads();
  for (int o = 1; o < 256; o <<= 1){
    int a = (t >= o) ? scn[t-o] : 0;
    __syncthreads();
    scn[t] += a;
    __syncthreads();
  }
  if (t < nd) off[d0 + t] = base + scn[t] - deg[t];
  __syncthreads();
  for (int s = t; s < cnt; s += 256){
    int2 rec = part[base + s];
    int dl = (rec.x >> 17) & 255;
    int p = base + scn[dl] - deg[dl] + atomicAdd(&c2[dl], 1);
    csr[p] = make_int2(rec.x & 0x1FFFF, rec.y);
  }
}

// ---------- 0. pre-convert weights to transposed bf16 (once per launch) ----------
__global__ __launch_bounds__(256) void k_cvtW(const float* __restrict__ W0, const float* __restrict__ W1,
                                              unsigned short* __restrict__ W0t, unsigned short* __restrict__ W1t){
  int t = blockIdx.x*256 + threadIdx.x;
  if (t < 128*128){ int k = t >> 7, c = t & 127; W0t[c*128 + k] = f2bf(W0[t]); }
  int u = t - 128*128;
  if (u >= 0 && u < 128*64){ int k = u >> 6, c = u & 63; W1t[c*128 + k] = f2bf(W1[u]); }
}

// ---------- GEMM1 (MFMA): Y(bf16) = x(f32) @ W0  (n x 128 @ 128 x 128) ----------
__global__ __launch_bounds__(256) void k_gemm1(const float* __restrict__ A, const unsigned short* __restrict__ Wg,
                                               unsigned short* __restrict__ Y, int n){
  __shared__ unsigned short Wt[128*WPITCH];    // 34.8 KB
  const int tid = threadIdx.x;
  for (int i = tid; i < 128*16; i += 256){     // straight bf16 copy, pitch insert
    int r = i >> 4, c = (i & 15) << 3;
    *(uint4*)(Wt + r*WPITCH + c) = *(const uint4*)(Wg + r*128 + c);
  }
  __syncthreads();
  const int lane = tid & 63, wv = tid >> 6;
  const int r0 = blockIdx.x*64 + wv*16;
  int rA = r0 + (lane & 15); if (rA > n-1) rA = n-1;
  const int kq = (lane >> 4) << 3;             // 0,8,16,24
  f32x4 acc[8] = {};
  #pragma unroll
  for (int kk = 0; kk < 4; ++kk){
    const float* ap = A + (size_t)rA*NF + kk*32 + kq;
    float4 a0 = *(const float4*)ap;
    float4 a1 = *(const float4*)(ap + 4);
    bf16x8 af;
    af[0]=(short)f2bf(a0.x); af[1]=(short)f2bf(a0.y); af[2]=(short)f2bf(a0.z); af[3]=(short)f2bf(a0.w);
    af[4]=(short)f2bf(a1.x); af[5]=(short)f2bf(a1.y); af[6]=(short)f2bf(a1.z); af[7]=(short)f2bf(a1.w);
    const unsigned short* wp = Wt + (lane & 15)*WPITCH + kk*32 + kq;
    #pragma unroll
    for (int nt = 0; nt < 8; ++nt){
      bf16x8 bf = *(const bf16x8*)(wp + nt*16*WPITCH);
      acc[nt] = __builtin_amdgcn_mfma_f32_16x16x32_bf16(af, bf, acc[nt], 0, 0, 0);
    }
  }
  const int rb = r0 + ((lane >> 4) << 2);      // D: col=nt*16+(lane&15), row=rb+j
  #pragma unroll
  for (int j = 0; j < 4; ++j){
    int rg = rb + j;
    if (rg < n){
      unsigned short* yp = Y + (size_t)rg*NF + (lane & 15);
      #pragma unroll
      for (int nt = 0; nt < 8; ++nt) yp[nt*16] = f2bf(acc[nt][j]);
    }
  }
}

// ---------- GEMM2 (MFMA): G(bf16) = h(bf16) @ W1  (n x 128 @ 128 x 64) ----------
__global__ __launch_bounds__(256) void k_gemm2(const unsigned short* __restrict__ Ab, const unsigned short* __restrict__ Wg,
                                               unsigned short* __restrict__ G, int n){
  __shared__ unsigned short Wt[64*WPITCH];     // 17.4 KB
  const int tid = threadIdx.x;
  for (int i = tid; i < 64*16; i += 256){
    int r = i >> 4, c = (i & 15) << 3;
    *(uint4*)(Wt + r*WPITCH + c) = *(const uint4*)(Wg + r*128 + c);
  }
  __syncthreads();
  const int lane = tid & 63, wv = tid >> 6;
  const int r0 = blockIdx.x*64 + wv*16;
  int rA = r0 + (lane & 15); if (rA > n-1) rA = n-1;
  const int kq = (lane >> 4) << 3;
  f32x4 acc[4] = {};
  #pragma unroll
  for (int kk = 0; kk < 4; ++kk){
    bf16x8 af = *(const bf16x8*)(Ab + (size_t)rA*NF + kk*32 + kq);
    const unsigned short* wp = Wt + (lane & 15)*WPITCH + kk*32 + kq;
    #pragma unroll
    for (int nt = 0; nt < 4; ++nt){
      bf16x8 bf = *(const bf16x8*)(wp + nt*16*WPITCH);
      acc[nt] = __builtin_amdgcn_mfma_f32_16x16x32_bf16(af, bf, acc[nt], 0, 0, 0);
    }
  }
  const int rb = r0 + ((lane >> 4) << 2);
  #pragma unroll
  for (int j = 0; j < 4; ++j){
    int rg = rb + j;
    if (rg < n){
      unsigned short* gp = G + (size_t)rg*NC + (lane & 15);
      #pragma unroll
      for (int nt = 0; nt < 4; ++nt) gp[nt*16] = f2bf(acc[nt][j]);
    }
  }
}

// ---------- SpMM1 + bias + ReLU: h(bf16) = relu(A@y + b0); s_load edge batches ----------
__global__ __launch_bounds__(256) void k_spmm_relu(const unsigned short* __restrict__ y, const int2* __restrict__ csr,
    const int* __restrict__ off, const float* __restrict__ bias, unsigned short* __restrict__ h, int n){
  int wid  = (blockIdx.x * 256 + threadIdx.x) >> 6;
  int lane = threadIdx.x & 63;
  if (wid >= n) return;
  const int s = __builtin_amdgcn_readfirstlane(off[wid]);
  const int e = __builtin_amdgcn_readfirstlane(off[wid+1]);
  float ax[8], ay[8];
  #pragma unroll
  for (int k = 0; k < 8; ++k){ ax[k] = 0.f; ay[k] = 0.f; }
  for (int jb = s & ~7; jb < e; jb += 8){      // 64B-aligned batches
    i32x16 rec = sload16(csr + jb);            // 8 records in SGPRs
    #pragma unroll
    for (int k = 0; k < 8; ++k){
      int idx = jb + k;
      bool in = (idx >= s) & (idx < e);        // scalar mask
      int row = in ? rec[2*k]   : 0;
      int wb  = in ? rec[2*k+1] : 0;
      unsigned v = ((const unsigned*)(y + (size_t)row * NF))[lane];  // saddr gather, 256B/row
      float w = __int_as_float(wb);
      ax[k] = fmaf(w, bflo(v), ax[k]);
      ay[k] = fmaf(w, bfhi(v), ay[k]);
    }
  }
  float sx = ((ax[0]+ax[1]) + (ax[2]+ax[3])) + ((ax[4]+ax[5]) + (ax[6]+ax[7]));
  float sy = ((ay[0]+ay[1]) + (ay[2]+ay[3])) + ((ay[4]+ay[5]) + (ay[6]+ay[7]));
  float2 bb = ((const float2*)bias)[lane];
  sx = fmaxf(sx + bb.x, 0.f);
  sy = fmaxf(sy + bb.y, 0.f);
  unsigned hv = (unsigned)f2bf(sx) | ((unsigned)f2bf(sy) << 16);
  *(unsigned*)(h + (size_t)wid * NF + lane*2) = hv;
}

// ---------- SpMM2 + bias + log_softmax: out = ls(A@g + b1); lane==class ----------
__global__ __launch_bounds__(256) void k_spmm_ls(const unsigned short* __restrict__ g, const int2* __restrict__ csr,
    const int* __restrict__ off, const float* __restrict__ bias, float* __restrict__ out, int n){
  int wid  = (blockIdx.x * 256 + threadIdx.x) >> 6;
  int lane = threadIdx.x & 63;
  if (wid >= n) return;
  const int s = __builtin_amdgcn_readfirstlane(off[wid]);
  const int e = __builtin_amdgcn_readfirstlane(off[wid+1]);
  float z[8];
  #pragma unroll
  for (int k = 0; k < 8; ++k) z[k] = 0.f;
  for (int jb = s & ~7; jb < e; jb += 8){
    i32x16 rec = sload16(csr + jb);
    #pragma unroll
    for (int k = 0; k < 8; ++k){
      int idx = jb + k;
      bool in = (idx >= s) & (idx < e);
      int row = in ? rec[2*k]   : 0;
      int wb  = in ? rec[2*k+1] : 0;
      unsigned short v = (g + (size_t)row * NC)[lane];  // saddr gather, 128B/row
      z[k] = fmaf(__int_as_float(wb), bflo((unsigned)v), z[k]);
    }
  }
  float zz = ((z[0]+z[1]) + (z[2]+z[3])) + ((z[4]+z[5]) + (z[6]+z[7]));
  zz += bias[lane];
  float m = zz;
  for (int o = 32; o; o >>= 1) m = fmaxf(m, __shfl_xor(m, o));
  float sum = expf(zz - m);
  for (int o = 32; o; o >>= 1) sum += __shfl_xor(sum, o);
  out[(size_t)wid * NC + lane] = zz - m - logf(sum);
}

extern "C" void kernel_launch(void* const* d_in, const int* in_sizes, int n_in,
                              void* d_out, int out_size, void* d_ws, size_t ws_size,
                              hipStream_t stream){
  const float* x  = (const float*)d_in[0];
  const int* esrc = (const int*)d_in[1];
  const int* edst = (const int*)d_in[2];
  const float* ew = (const float*)d_in[3];
  const float* W0 = (const float*)d_in[4];
  const float* b0 = (const float*)d_in[5];
  const float* W1 = (const float*)d_in[6];
  const float* b1 = (const float*)d_in[7];
  float* out = (float*)d_out;

  const int N = in_sizes[0] / NF;
  const int E = in_sizes[1];
  const int NB = (N + 255) >> 8;            // 391 buckets of 256 dsts

  char* ws = (char*)d_ws;
  size_t o = 0;
  int*  bhist = (int*) (ws + o); o = alignup(o + NBMAX*4);
  int*  bbase = (int*) (ws + o); o = alignup(o + NBMAX*4);
  int*  bcur  = (int*) (ws + o); o = alignup(o + NBMAX*4);
  int*  off   = (int*) (ws + o); o = alignup(o + (size_t)(N+1)*4);
  unsigned short* W0t = (unsigned short*)(ws + o); o = alignup(o + 128*128*2);
  unsigned short* W1t = (unsigned short*)(ws + o); o = alignup(o + 128*64*2);
  int2* part  = (int2*)(ws + o); o = alignup(o + (size_t)E*8);
  int2* csr   = (int2*)(ws + o); o = alignup(o + (size_t)E*8 + 64);   // +64B s_load overrun pad
  unsigned short* y  = (unsigned short*)(ws + o); o = alignup(o + (size_t)N*NF*2);  // bf16; reused as g
  unsigned short* hb = (unsigned short*)(ws + o); o = alignup(o + (size_t)N*NF*2);  // bf16 h
  unsigned short* g = y;  // y dead after k_spmm_relu

  hipMemsetAsync(bhist, 0, NBMAX*4, stream);

  const int hbk = (E + 4095)/4096;
  const int pb = (E + TPART-1)/TPART;

  k_cvtW <<<96, 256, 0, stream>>>(W0, W1, W0t, W1t);
  k_hist <<<hbk, 256, 0, stream>>>(edst, bhist, E, NB);
  k_bscan<<<1, 512, 0, stream>>>(bhist, bbase, bcur, off, NB, N);
  k_part <<<pb, 512, 0, stream>>>(esrc, edst, ew, bcur, part, E, NB);
  k_fill2<<<NB, 256, 0, stream>>>(part, bhist, bbase, off, csr, N);

  const int gb = (N + 63)/64;               // 4 waves x 16 rows per block
  const int sb = (N + 3)/4;

  k_gemm1<<<gb, 256, 0, stream>>>(x, W0t, y, N);               // y = bf16(x @ W0)   [MFMA]
  k_spmm_relu<<<sb, 256, 0, stream>>>(y, csr, off, b0, hb, N); // hb = bf16(relu(A y + b0))
  k_gemm2<<<gb, 256, 0, stream>>>(hb, W1t, g, N);              // g = bf16(hb @ W1)  [MFMA]
  k_spmm_ls<<<sb, 256, 0, stream>>>(g, csr, off, b1, out, N);  // out = log_softmax(A g + b1)
}